// Round 8
// baseline (30.974 us; speedup 1.0000x reference)
//
#include <hip/hip_runtime.h>
#include <hip/hip_fp16.h>

#define N_REL 201   // NUM_RELS + 1 (PAD row 200 is all-zero)
#define N_TGT 200   // target_rels < 200
#define SEM 32      // SEM_DIM
#define KNEI 20     // K neighbors
#define PSTRIDE 40  // halfs per P row (80 B -> uniform 8-class bank phases)

typedef float floatx4 __attribute__((ext_vector_type(4)));  // NT-builtin-compatible

// Workspace layout:
//   [0, 80400)        __half S_T[200][201]   (S_T[tgt][idx] = emb_idx . emb_tgt)
//   [80400, +32160)   __half P[402][PSTRIDE] (cols 0..31 valid, bias/2 folded)
#define ST_BYTES 80400                 // 16-aligned (16*5025)
#define P_HALFS (2 * N_REL * PSTRIDE)  // 16080
#define P_U4 (P_HALFS * 2 / 16)        // 2010

#define EMB_STRIDE 68   // floats/row: 16B-aligned, dword-stride 17 (odd) -> 32 bank phases
#define WL_STRIDE 132   // floats/row: 16B-aligned, dword-stride 33 (odd)

// ---------------------------------------------------------------------------
// Kernel 1 (vectorized): S_T[j][i] = emb[i]·emb[j] (fp16); P with bias/2 folded.
// float4 staging + float4 LDS dot products (32 ds_read_b128 + 64 FMA per row).
// ---------------------------------------------------------------------------
__global__ __launch_bounds__(256) void build_tables_kernel(
    const float* __restrict__ rel_emb,   // [201][64]
    const float* __restrict__ w,         // [32][128]
    const float* __restrict__ bias,      // [32]
    __half* __restrict__ St,             // [200][201] transposed
    __half* __restrict__ P)              // [402][PSTRIDE]
{
  __shared__ __align__(16) float embL[N_REL * EMB_STRIDE];  // 54,672 B
  __shared__ __align__(16) float wL[SEM * WL_STRIDE];       // 16,896 B
  const int t = threadIdx.x;
  // staging: 3216 + 1024 float4s, fully coalesced
  for (int e = t; e < N_REL * 16; e += 256) {
    const int r = e >> 4, s = e & 15;
    *(float4*)&embL[r * EMB_STRIDE + s * 4] = ((const float4*)rel_emb)[e];
  }
  for (int e = t; e < SEM * 32; e += 256) {
    const int r = e >> 5, s = e & 31;
    *(float4*)&wL[r * WL_STRIDE + s * 4] = ((const float4*)w)[e];
  }
  __syncthreads();

  const int i = blockIdx.x;  // 0..200 (idx dimension)
  const float4* __restrict__ ri = (const float4*)&embL[i * EMB_STRIDE];
  for (int jj = t; jj < N_TGT; jj += 256) {
    const float4* __restrict__ rj = (const float4*)&embL[jj * EMB_STRIDE];
    float acc = 0.f;
#pragma unroll
    for (int d = 0; d < 16; ++d) {
      const float4 a = ri[d], b = rj[d];
      acc = fmaf(a.x, b.x, acc);
      acc = fmaf(a.y, b.y, acc);
      acc = fmaf(a.z, b.z, acc);
      acc = fmaf(a.w, b.w, acc);
    }
    St[jj * N_REL + i] = __float2half(acc);   // transposed store
  }
  if (t < 64) {
    const int hh = t >> 5, jj = t & 31;
    const float4* __restrict__ rw = (const float4*)&wL[jj * WL_STRIDE + hh * 64];
    float acc = 0.5f * bias[jj];
#pragma unroll
    for (int d = 0; d < 16; ++d) {
      const float4 a = ri[d], b = rw[d];
      acc = fmaf(a.x, b.x, acc);
      acc = fmaf(a.y, b.y, acc);
      acc = fmaf(a.z, b.z, acc);
      acc = fmaf(a.w, b.w, acc);
    }
    P[(hh * N_REL + i) * PSTRIDE + jj] = __float2half(acc);
  }
}

// ---------------------------------------------------------------------------
// Kernel 2: 8 LANES PER NODE, 512-thr blocks — identical structure to r7
// (for the double-launch split measurement), plus quad-coalesced idx loads
// via interleaved k-assignment (lane q owns k in {q, 4+q, ..., 16+q}).
// ---------------------------------------------------------------------------
__global__ __launch_bounds__(512, 4) void fuse_kernel(
    const int* __restrict__ out_nei, const int* __restrict__ in_nei,
    const int* __restrict__ target, const float* __restrict__ feat,
    const __half* __restrict__ St, const __half* __restrict__ Pg,
    float* __restrict__ out, int n_nodes)
{
  __shared__ __align__(16) __half P_l[P_HALFS];    // 32160 B
  const int t = threadIdx.x;
  const int gid = blockIdx.x * 512 + t;
  const int n = gid >> 3;
  const int sub = t & 7;
  const int dir = sub >> 2;   // 0 = out, 1 = in
  const int q = sub & 3;      // 8-dim slice / k-phase
  const bool active = (n < n_nodes);

  // ---- phase 1: issue ALL dependent-chain loads (latency hides under staging)
  int idxA[5];
  unsigned short sv[5];
  floatx4 f0, f1;
  if (active) {
    const int tgt = target[n];
    const int* __restrict__ nei = dir ? in_nei : out_nei;
#pragma unroll
    for (int i = 0; i < 5; ++i) idxA[i] = nei[(size_t)n * KNEI + 4 * i + q];
    const __half* __restrict__ srow = St + (size_t)tgt * N_REL;
#pragma unroll
    for (int i = 0; i < 5; ++i)
      sv[i] = *(const unsigned short*)&srow[idxA[i]];
    if (dir == 0) {
      const floatx4* frow = (const floatx4*)(feat + (size_t)n * SEM + q * 8);
      f0 = __builtin_nontemporal_load(frow);
      f1 = __builtin_nontemporal_load(frow + 1);
    }
  }

  // ---- phase 2: stage P into LDS (covers phase-1 latency) ----
  {
    const uint4* p4 = (const uint4*)Pg;
    uint4* pl = (uint4*)P_l;
    for (int e = t; e < P_U4; e += 512) pl[e] = p4[e];
  }
  __syncthreads();
  if (!active) return;

  // ---- phase 3: register-resident compute ----
  float ev[5];
#pragma unroll
  for (int i = 0; i < 5; ++i) ev[i] = __half2float(__ushort_as_half(sv[i]));

  // softmax over the dir's 20 scores (quad butterfly, DPP-cheap)
  float mx = ev[0];
#pragma unroll
  for (int i = 1; i < 5; ++i) mx = fmaxf(mx, ev[i]);
  mx = fmaxf(mx, __shfl_xor(mx, 1, 64));
  mx = fmaxf(mx, __shfl_xor(mx, 2, 64));
  float s = 0.f;
#pragma unroll
  for (int i = 0; i < 5; ++i) {
    ev[i] = __expf(ev[i] - mx);
    s += ev[i];
  }
  s += __shfl_xor(s, 1, 64);
  s += __shfl_xor(s, 2, 64);
  const float inv = __fdividef(1.f, s);

  // pack {idx | w_fp16}; all-gather within the dir quad (15 shuffles)
  unsigned int pk[20];
#pragma unroll
  for (int i = 0; i < 5; ++i) {
    const __half hw = __float2half(ev[i] * inv);
    pk[i] = ((unsigned int)idxA[i] << 16) | (unsigned int)__half_as_ushort(hw);
  }
#pragma unroll
  for (int i = 0; i < 5; ++i) pk[5 + i] = __shfl_xor(pk[i], 1, 64);
#pragma unroll
  for (int i = 0; i < 10; ++i) pk[10 + i] = __shfl_xor(pk[i], 2, 64);

  // aggregate 20 rows, own 8-dim slice (1 b128 per row)
  __half2 acc[4];
#pragma unroll
  for (int m = 0; m < 4; ++m) acc[m] = __float2half2_rn(0.f);
  const int dbase = dir * (N_REL * PSTRIDE) + q * 8;
#pragma unroll
  for (int i = 0; i < 20; ++i) {
    const int idx = (int)(pk[i] >> 16);
    const unsigned int lo = pk[i] & 0xFFFFu;
    const unsigned int dd = lo | (lo << 16);
    const __half2 a2 = *(const __half2*)&dd;
    const uint4 qv = *(const uint4*)&P_l[dbase + idx * PSTRIDE];
    acc[0] = __hfma2(a2, *(const __half2*)&qv.x, acc[0]);
    acc[1] = __hfma2(a2, *(const __half2*)&qv.y, acc[1]);
    acc[2] = __hfma2(a2, *(const __half2*)&qv.z, acc[2]);
    acc[3] = __hfma2(a2, *(const __half2*)&qv.w, acc[3]);
  }

  // combine directions: partner lane = lane ^ 4
#pragma unroll
  for (int m = 0; m < 4; ++m) {
    const unsigned int u = *(const unsigned int*)&acc[m];
    const unsigned int v = __shfl_xor(u, 4, 64);
    acc[m] = __hadd2(acc[m], *(const __half2*)&v);
  }

  // write: lanes 0-3 -> feat slice, lanes 4-7 -> sigmoid sem slice (NT stores)
  float* orow = out + (size_t)n * 64 + sub * 8;
  if (dir == 0) {
    __builtin_nontemporal_store(f0, (floatx4*)orow);
    __builtin_nontemporal_store(f1, (floatx4*)orow + 1);
  } else {
    float tv[8];
#pragma unroll
    for (int m = 0; m < 4; ++m) {
      tv[2 * m]     = __low2float(acc[m]);
      tv[2 * m + 1] = __high2float(acc[m]);
    }
    floatx4 s0, s1;
    s0.x = __fdividef(1.f, 1.f + __expf(-tv[0]));
    s0.y = __fdividef(1.f, 1.f + __expf(-tv[1]));
    s0.z = __fdividef(1.f, 1.f + __expf(-tv[2]));
    s0.w = __fdividef(1.f, 1.f + __expf(-tv[3]));
    s1.x = __fdividef(1.f, 1.f + __expf(-tv[4]));
    s1.y = __fdividef(1.f, 1.f + __expf(-tv[5]));
    s1.z = __fdividef(1.f, 1.f + __expf(-tv[6]));
    s1.w = __fdividef(1.f, 1.f + __expf(-tv[7]));
    __builtin_nontemporal_store(s0, (floatx4*)orow);
    __builtin_nontemporal_store(s1, (floatx4*)orow + 1);
  }
}

extern "C" void kernel_launch(void* const* d_in, const int* in_sizes, int n_in,
                              void* d_out, int out_size, void* d_ws, size_t ws_size,
                              hipStream_t stream) {
  const int* out_nei   = (const int*)d_in[0];
  const int* in_nei    = (const int*)d_in[1];
  const int* target    = (const int*)d_in[2];
  const float* feat    = (const float*)d_in[3];
  const float* rel_emb = (const float*)d_in[4];
  const float* w       = (const float*)d_in[5];
  const float* bias    = (const float*)d_in[6];
  float* out = (float*)d_out;
  const int n_nodes = in_sizes[2];

  __half* St = (__half*)d_ws;
  __half* P  = (__half*)((char*)d_ws + ST_BYTES);

  build_tables_kernel<<<N_REL, 256, 0, stream>>>(rel_emb, w, bias, St, P);
  const int total_threads = n_nodes * 8;
  const int nb = (total_threads + 511) / 512;   // 782 blocks @ N=50000
  // PROBE: launch fuse TWICE (idempotent -> identical output, deterministic).
  // dur = build' + 2*fuse + 3*launch; next round reverts to one launch so
  // fuse+launch = dur_r8 - dur_r9.
  fuse_kernel<<<nb, 512, 0, stream>>>(out_nei, in_nei, target, feat, St, P,
                                      out, n_nodes);
  fuse_kernel<<<nb, 512, 0, stream>>>(out_nei, in_nei, target, feat, St, P,
                                      out, n_nodes);
}

// Round 9
// 26.232 us; speedup vs baseline: 1.1808x; 1.1808x over previous
//
#include <hip/hip_runtime.h>
#include <hip/hip_fp16.h>

#define N_REL 201   // NUM_RELS + 1 (PAD row 200 is all-zero)
#define N_TGT 200   // target_rels < 200
#define SEM 32      // SEM_DIM
#define KNEI 20     // K neighbors
#define PSTRIDE 32  // halfs per P row: 64 B = one cache line per row

typedef float floatx4 __attribute__((ext_vector_type(4)));  // NT-builtin-compatible

// Workspace layout:
//   [0, 80400)        __half S_T[200][201]   (S_T[tgt][idx] = emb_idx . emb_tgt)
//   [80400, +25728)   __half P[402][32]      (bias/2 folded; 64B line-aligned rows)
#define ST_BYTES 80400                 // 16-aligned (16*5025)
#define P_HALFS (2 * N_REL * PSTRIDE)  // 12864

#define EMB_STRIDE 68   // floats/row: 16B-aligned, dword-stride 17 (odd) -> 32 bank phases
#define WL_STRIDE 132   // floats/row: 16B-aligned, dword-stride 33 (odd)

// ---------------------------------------------------------------------------
// Kernel 1 (vectorized): S_T[j][i] = emb[i]·emb[j] (fp16); P with bias/2 folded.
// ---------------------------------------------------------------------------
__global__ __launch_bounds__(256) void build_tables_kernel(
    const float* __restrict__ rel_emb,   // [201][64]
    const float* __restrict__ w,         // [32][128]
    const float* __restrict__ bias,      // [32]
    __half* __restrict__ St,             // [200][201] transposed
    __half* __restrict__ P)              // [402][PSTRIDE]
{
  __shared__ __align__(16) float embL[N_REL * EMB_STRIDE];  // 54,672 B
  __shared__ __align__(16) float wL[SEM * WL_STRIDE];       // 16,896 B
  const int t = threadIdx.x;
  for (int e = t; e < N_REL * 16; e += 256) {
    const int r = e >> 4, s = e & 15;
    *(float4*)&embL[r * EMB_STRIDE + s * 4] = ((const float4*)rel_emb)[e];
  }
  for (int e = t; e < SEM * 32; e += 256) {
    const int r = e >> 5, s = e & 31;
    *(float4*)&wL[r * WL_STRIDE + s * 4] = ((const float4*)w)[e];
  }
  __syncthreads();

  const int i = blockIdx.x;  // 0..200 (idx dimension)
  const float4* __restrict__ ri = (const float4*)&embL[i * EMB_STRIDE];
  for (int jj = t; jj < N_TGT; jj += 256) {
    const float4* __restrict__ rj = (const float4*)&embL[jj * EMB_STRIDE];
    float acc = 0.f;
#pragma unroll
    for (int d = 0; d < 16; ++d) {
      const float4 a = ri[d], b = rj[d];
      acc = fmaf(a.x, b.x, acc);
      acc = fmaf(a.y, b.y, acc);
      acc = fmaf(a.z, b.z, acc);
      acc = fmaf(a.w, b.w, acc);
    }
    St[jj * N_REL + i] = __float2half(acc);   // transposed store
  }
  if (t < 64) {
    const int hh = t >> 5, jj = t & 31;
    const float4* __restrict__ rw = (const float4*)&wL[jj * WL_STRIDE + hh * 64];
    float acc = 0.5f * bias[jj];
#pragma unroll
    for (int d = 0; d < 16; ++d) {
      const float4 a = ri[d], b = rw[d];
      acc = fmaf(a.x, b.x, acc);
      acc = fmaf(a.y, b.y, acc);
      acc = fmaf(a.z, b.z, acc);
      acc = fmaf(a.w, b.w, acc);
    }
    P[(hh * N_REL + i) * PSTRIDE + jj] = __float2half(acc);
  }
}

// ---------------------------------------------------------------------------
// Kernel 2: 8 LANES PER NODE, NO LDS, NO BARRIER. P (25.7 KB) is L1-resident;
// read rows directly from global. Pure streaming: idx -> S gather -> softmax
// (quad shuffles) -> 20 L1-hot 16B P gathers -> cross-dir shuffle -> NT store.
// 256-thr blocks, 8 waves/SIMD occupancy (no LDS, ~52 VGPR).
// ---------------------------------------------------------------------------
__global__ __launch_bounds__(256, 8) void fuse_kernel(
    const int* __restrict__ out_nei, const int* __restrict__ in_nei,
    const int* __restrict__ target, const float* __restrict__ feat,
    const __half* __restrict__ St, const __half* __restrict__ Pg,
    float* __restrict__ out, int n_nodes)
{
  const int t = threadIdx.x;
  const int gid = blockIdx.x * 256 + t;
  const int n = gid >> 3;
  if (n >= n_nodes) return;
  const int sub = t & 7;
  const int dir = sub >> 2;   // 0 = out, 1 = in
  const int q = sub & 3;      // 8-dim slice / k-phase

  // ---- issue independent loads up front ----
  const int tgt = target[n];
  const int* __restrict__ nei = dir ? in_nei : out_nei;
  int idxA[5];
#pragma unroll
  for (int i = 0; i < 5; ++i) idxA[i] = nei[(size_t)n * KNEI + 4 * i + q];
  floatx4 f0, f1;
  if (dir == 0) {
    const floatx4* frow = (const floatx4*)(feat + (size_t)n * SEM + q * 8);
    f0 = __builtin_nontemporal_load(frow);
    f1 = __builtin_nontemporal_load(frow + 1);
  }
  const __half* __restrict__ srow = St + (size_t)tgt * N_REL;
  float ev[5];
#pragma unroll
  for (int i = 0; i < 5; ++i)
    ev[i] = __half2float(srow[idxA[i]]);

  // ---- softmax over the dir's 20 scores (quad butterfly, DPP-cheap) ----
  float mx = ev[0];
#pragma unroll
  for (int i = 1; i < 5; ++i) mx = fmaxf(mx, ev[i]);
  mx = fmaxf(mx, __shfl_xor(mx, 1, 64));
  mx = fmaxf(mx, __shfl_xor(mx, 2, 64));
  float s = 0.f;
#pragma unroll
  for (int i = 0; i < 5; ++i) {
    ev[i] = __expf(ev[i] - mx);
    s += ev[i];
  }
  s += __shfl_xor(s, 1, 64);
  s += __shfl_xor(s, 2, 64);
  const float inv = __fdividef(1.f, s);

  // ---- pack {idx | w_fp16}; all-gather within the dir quad (15 shuffles) ----
  unsigned int pk[20];
#pragma unroll
  for (int i = 0; i < 5; ++i) {
    const __half hw = __float2half(ev[i] * inv);
    pk[i] = ((unsigned int)idxA[i] << 16) | (unsigned int)__half_as_ushort(hw);
  }
#pragma unroll
  for (int i = 0; i < 5; ++i) pk[5 + i] = __shfl_xor(pk[i], 1, 64);
#pragma unroll
  for (int i = 0; i < 10; ++i) pk[10 + i] = __shfl_xor(pk[i], 2, 64);

  // ---- aggregate 20 rows, own 8-dim slice: 16B L1-hot global gathers ----
  __half2 acc[4];
#pragma unroll
  for (int m = 0; m < 4; ++m) acc[m] = __float2half2_rn(0.f);
  const __half* __restrict__ pbase = Pg + dir * (N_REL * PSTRIDE) + q * 8;
#pragma unroll
  for (int i = 0; i < 20; ++i) {
    const int idx = (int)(pk[i] >> 16);
    const unsigned int lo = pk[i] & 0xFFFFu;
    const unsigned int dd = lo | (lo << 16);
    const __half2 a2 = *(const __half2*)&dd;
    const uint4 qv = *(const uint4*)(pbase + idx * PSTRIDE);
    acc[0] = __hfma2(a2, *(const __half2*)&qv.x, acc[0]);
    acc[1] = __hfma2(a2, *(const __half2*)&qv.y, acc[1]);
    acc[2] = __hfma2(a2, *(const __half2*)&qv.z, acc[2]);
    acc[3] = __hfma2(a2, *(const __half2*)&qv.w, acc[3]);
  }

  // ---- combine directions: partner lane = lane ^ 4 ----
#pragma unroll
  for (int m = 0; m < 4; ++m) {
    const unsigned int u = *(const unsigned int*)&acc[m];
    const unsigned int v = __shfl_xor(u, 4, 64);
    acc[m] = __hadd2(acc[m], *(const __half2*)&v);
  }

  // ---- write: lanes 0-3 -> feat slice, lanes 4-7 -> sigmoid slice (NT) ----
  float* orow = out + (size_t)n * 64 + sub * 8;
  if (dir == 0) {
    __builtin_nontemporal_store(f0, (floatx4*)orow);
    __builtin_nontemporal_store(f1, (floatx4*)orow + 1);
  } else {
    float tv[8];
#pragma unroll
    for (int m = 0; m < 4; ++m) {
      tv[2 * m]     = __low2float(acc[m]);
      tv[2 * m + 1] = __high2float(acc[m]);
    }
    floatx4 s0, s1;
    s0.x = __fdividef(1.f, 1.f + __expf(-tv[0]));
    s0.y = __fdividef(1.f, 1.f + __expf(-tv[1]));
    s0.z = __fdividef(1.f, 1.f + __expf(-tv[2]));
    s0.w = __fdividef(1.f, 1.f + __expf(-tv[3]));
    s1.x = __fdividef(1.f, 1.f + __expf(-tv[4]));
    s1.y = __fdividef(1.f, 1.f + __expf(-tv[5]));
    s1.z = __fdividef(1.f, 1.f + __expf(-tv[6]));
    s1.w = __fdividef(1.f, 1.f + __expf(-tv[7]));
    __builtin_nontemporal_store(s0, (floatx4*)orow);
    __builtin_nontemporal_store(s1, (floatx4*)orow + 1);
  }
}

extern "C" void kernel_launch(void* const* d_in, const int* in_sizes, int n_in,
                              void* d_out, int out_size, void* d_ws, size_t ws_size,
                              hipStream_t stream) {
  const int* out_nei   = (const int*)d_in[0];
  const int* in_nei    = (const int*)d_in[1];
  const int* target    = (const int*)d_in[2];
  const float* feat    = (const float*)d_in[3];
  const float* rel_emb = (const float*)d_in[4];
  const float* w       = (const float*)d_in[5];
  const float* bias    = (const float*)d_in[6];
  float* out = (float*)d_out;
  const int n_nodes = in_sizes[2];

  __half* St = (__half*)d_ws;
  __half* P  = (__half*)((char*)d_ws + ST_BYTES);

  build_tables_kernel<<<N_REL, 256, 0, stream>>>(rel_emb, w, bias, St, P);
  const int total_threads = n_nodes * 8;
  const int nb = (total_threads + 255) / 256;   // 1563 blocks @ N=50000
  fuse_kernel<<<nb, 256, 0, stream>>>(out_nei, in_nei, target, feat, St, P,
                                      out, n_nodes);
}